// Round 1
// baseline (261.397 us; speedup 1.0000x reference)
//
#include <hip/hip_runtime.h>

typedef unsigned short u16;
typedef __bf16 bf16x8 __attribute__((ext_vector_type(8)));
typedef float f32x4 __attribute__((ext_vector_type(4)));

#define MFMA(a, b, c) __builtin_amdgcn_mfma_f32_16x16x32_bf16((a), (b), (c), 0, 0, 0)

__device__ __forceinline__ u16 f2bf(float f) {
    unsigned u = __float_as_uint(f);
    unsigned r = (u + 0x7fffu + ((u >> 16) & 1u)) >> 16;  // RNE
    return (u16)r;
}
__device__ __forceinline__ float bf2f(u16 h) { return __uint_as_float(((unsigned)h) << 16); }

// ---------------------------------------------------------------------------
// Shapes: b=16, c=256, H=W=64 -> n=4096, heads=8, dim_head=32, 3*hd = 768
// x layout: (b, c, n). Output: (b, c, n) fp32.
// ---------------------------------------------------------------------------

// K1: fused LayerNorm stats + normalize + transpose: x (b,c,n) fp32 -> xlnT (b,n,c) bf16
// block: 64 n-positions x all 256 c.  grid = 16*64 = 1024
__global__ __launch_bounds__(256) void k_ln(const float* __restrict__ x,
                                            const float* __restrict__ gamma,
                                            const float* __restrict__ beta,
                                            u16* __restrict__ xlnT) {
    int bid = blockIdx.x;
    int b = bid >> 6, nt = bid & 63;
    int nb = nt * 64;
    __shared__ unsigned xsu[256 * 33];  // packed bf16 pairs: [c][n-pair], pad 33
    __shared__ float muv[64], rsv[64];
    __shared__ float redS[8 * 64], redS2[8 * 64];
    int t = threadIdx.x;
    // phase 1: load coalesced (float2 along n), pack to bf16 pairs
    {
        int np = t & 31;       // n-pair index (n = 2*np, 2*np+1)
        int c0 = t >> 5;       // 0..7
        const float* xp = x + ((size_t)b * 256) * 4096 + nb + np * 2;
        for (int i = 0; i < 32; i++) {
            int c = c0 + i * 8;
            float2 f = *(const float2*)(xp + (size_t)c * 4096);
            unsigned u = (unsigned)f2bf(f.x) | ((unsigned)f2bf(f.y) << 16);
            xsu[c * 33 + np] = u;
        }
    }
    __syncthreads();
    // phase 2: per-n mean/var over c
    {
        int np = t & 31, q = t >> 5;
        float s0 = 0, s20 = 0, s1 = 0, s21 = 0;
        for (int i = 0; i < 32; i++) {
            unsigned u = xsu[(q * 32 + i) * 33 + np];
            float a = bf2f((u16)(u & 0xffffu));
            float bv = bf2f((u16)(u >> 16));
            s0 += a; s20 += a * a; s1 += bv; s21 += bv * bv;
        }
        redS[q * 64 + np * 2] = s0;  redS[q * 64 + np * 2 + 1] = s1;
        redS2[q * 64 + np * 2] = s20; redS2[q * 64 + np * 2 + 1] = s21;
    }
    __syncthreads();
    if (t < 64) {
        float s = 0, s2 = 0;
        for (int q = 0; q < 8; q++) { s += redS[q * 64 + t]; s2 += redS2[q * 64 + t]; }
        float m = s * (1.f / 256.f);
        float var = s2 * (1.f / 256.f) - m * m;
        muv[t] = m;
        rsv[t] = rsqrtf(var + 1e-5f);
    }
    __syncthreads();
    // phase 3: write xlnT[b][n][c] bf16, lanes along c -> 512B contiguous stores
    {
        int c4 = (t & 63) * 4;
        int ng = t >> 6;
        float g[4], e[4];
        for (int j = 0; j < 4; j++) { g[j] = gamma[c4 + j]; e[j] = beta[c4 + j]; }
        for (int i = 0; i < 16; i++) {
            int n = ng * 16 + i;
            float m = muv[n], rs = rsv[n];
            u16 h[4];
            for (int j = 0; j < 4; j++) {
                unsigned u = xsu[(c4 + j) * 33 + (n >> 1)];
                u16 raw = (n & 1) ? (u16)(u >> 16) : (u16)(u & 0xffffu);
                float v = (bf2f(raw) - m) * rs * g[j] + e[j];
                h[j] = f2bf(v);
            }
            uint2 w2;
            w2.x = (unsigned)h[0] | ((unsigned)h[1] << 16);
            w2.y = (unsigned)h[2] | ((unsigned)h[3] << 16);
            *(uint2*)(xlnT + ((size_t)(b * 4096 + nb + n)) * 256 + c4) = w2;
        }
    }
}

// K2: transpose weights to bf16 [out_col][in_row], zero sims accumulator. grid=768
__global__ __launch_bounds__(256) void k_prep(const float* __restrict__ Wqkv,
                                              const float* __restrict__ Wout,
                                              u16* __restrict__ WqkvT, u16* __restrict__ WoutT,
                                              float* __restrict__ sims) {
    int i = blockIdx.x * 256 + threadIdx.x;
    if (i < 768 * 256) { int o = i >> 8, c = i & 255; WqkvT[i] = f2bf(Wqkv[c * 768 + o]); }
    if (i < 256 * 256) { int o = i >> 8, c = i & 255; WoutT[i] = f2bf(Wout[c * 256 + o]); }
    if (i < 128 * 1024) sims[i] = 0.f;
}

// K3/K8: GEMM  C[m][n] = A[m][0:256] . B^T[n][0:256]   (B stored row-major [n][k])
// A: bf16 [M][256] (M = mtiles*128), B: bf16 [b][4096][256], out cols n contiguous.
// mode 0: store bf16 to o16 (row stride-b 768*4096);  mode 1: fp32 + bias to o32 (row stride-b 256*4096)
__global__ __launch_bounds__(256) void k_gemm(const u16* __restrict__ A, const u16* __restrict__ Bb,
                                              int mtiles, u16* __restrict__ o16,
                                              float* __restrict__ o32, const float* __restrict__ bias,
                                              int mode) {
    int bid = blockIdx.x;
    int per_b = mtiles * 32;
    int b = bid / per_b;
    int r2 = bid % per_b;
    int mbase = (r2 >> 5) * 128, nbase = (r2 & 31) * 128;
    __shared__ u16 aT[128 * 40];  // [m][k] pad 40 (80B rows -> 2-way, free)
    __shared__ u16 bT[128 * 40];  // [n][k]
    int t = threadIdx.x, w = t >> 6, lane = t & 63, l15 = lane & 15, quad = lane >> 4;
    const u16* Bp = Bb + (size_t)b * 4096 * 256;
    f32x4 acc[2][8];
    f32x4 z = {0.f, 0.f, 0.f, 0.f};
    for (int fm = 0; fm < 2; fm++)
        for (int fn = 0; fn < 8; fn++) acc[fm][fn] = z;
    int arow = t >> 1, ac = (t & 1) * 16;
    for (int kt = 0; kt < 8; kt++) {
        int kb = kt * 32;
        if (kt) __syncthreads();
        {
            const uint4* g = (const uint4*)(A + (size_t)(mbase + arow) * 256 + kb + ac);
            uint4 p0 = g[0], p1 = g[1];
            *(uint4*)&aT[arow * 40 + ac] = p0;
            *(uint4*)&aT[arow * 40 + ac + 8] = p1;
        }
        {
            const uint4* g = (const uint4*)(Bp + (size_t)(nbase + arow) * 256 + kb + ac);
            uint4 p0 = g[0], p1 = g[1];
            *(uint4*)&bT[arow * 40 + ac] = p0;
            *(uint4*)&bT[arow * 40 + ac + 8] = p1;
        }
        __syncthreads();
        bf16x8 af0 = *(const bf16x8*)&aT[(w * 32 + l15) * 40 + quad * 8];
        bf16x8 af1 = *(const bf16x8*)&aT[(w * 32 + 16 + l15) * 40 + quad * 8];
        for (int fn = 0; fn < 8; fn++) {
            bf16x8 bfr = *(const bf16x8*)&bT[(fn * 16 + l15) * 40 + quad * 8];
            acc[0][fn] = MFMA(af0, bfr, acc[0][fn]);
            acc[1][fn] = MFMA(af1, bfr, acc[1][fn]);
        }
    }
    for (int fm = 0; fm < 2; fm++)
        for (int fn = 0; fn < 8; fn++)
            for (int r = 0; r < 4; r++) {
                int row = mbase + w * 32 + fm * 16 + quad * 4 + r;
                int col = nbase + fn * 16 + l15;
                float v = acc[fm][fn][r];
                if (mode == 0)
                    o16[((size_t)b * 768 + row) * 4096 + col] = f2bf(v);
                else
                    o32[((size_t)b * 256 + row) * 4096 + col] = v + bias[row];
            }
}

// K4: sum of squares per q/k row (o in [0,512)) over n=4096. grid = 16*64 = 1024
__global__ __launch_bounds__(256) void k_norms(const u16* __restrict__ qkv, float* __restrict__ normsq) {
    int bid = blockIdx.x;
    int b = bid >> 6, rg = bid & 63;
    int t = threadIdx.x;
    int r8 = t >> 5, l32 = t & 31;
    int o = rg * 8 + r8;  // 0..511
    const u16* p = qkv + ((size_t)b * 768 + o) * 4096 + l32 * 8;
    float s = 0.f;
    for (int i = 0; i < 16; i++) {
        uint4 u = *(const uint4*)(p + i * 256);
        const u16* us = (const u16*)&u;
        for (int jj = 0; jj < 8; jj++) { float f = bf2f(us[jj]); s += f * f; }
    }
    s += __shfl_down(s, 16, 32);
    s += __shfl_down(s, 8, 32);
    s += __shfl_down(s, 4, 32);
    s += __shfl_down(s, 2, 32);
    s += __shfl_down(s, 1, 32);
    if (l32 == 0) normsq[b * 512 + o] = s;
}

// K5: raw sim = q . k^T over n (per b,h), K split in 2, fp32 atomic accumulate.
// grid = 128*2 = 256.  Wave w -> 16x16 quadrant (ib = w>>1, jb = w&1).
__global__ __launch_bounds__(256) void k_sim(const u16* __restrict__ qkv, float* __restrict__ sims) {
    int bid = blockIdx.x;
    int bh = bid >> 1, half = bid & 1;
    int b = bh >> 3, h = bh & 7;
    __shared__ u16 qs[32 * 264];  // [row][k] pad 264 (528B rows)
    __shared__ u16 ks[32 * 264];
    int t = threadIdx.x, w = t >> 6, lane = t & 63, l15 = lane & 15, quad = lane >> 4;
    int ib = w >> 1, jb = w & 1;
    const u16* qbase = qkv + ((size_t)(b * 768) + h * 32) * 4096;
    const u16* kbase = qkv + ((size_t)(b * 768) + 256 + h * 32) * 4096;
    int col8 = t & 31, rb = t >> 5;
    f32x4 acc = {0.f, 0.f, 0.f, 0.f};
    for (int kc = 0; kc < 8; kc++) {
        int kb = half * 2048 + kc * 256;
        __syncthreads();
        for (int i = 0; i < 4; i++) {
            int r = rb + i * 8;
            uint4 pq = *(const uint4*)(qbase + (size_t)r * 4096 + kb + col8 * 8);
            *(uint4*)&qs[r * 264 + col8 * 8] = pq;
            uint4 pk = *(const uint4*)(kbase + (size_t)r * 4096 + kb + col8 * 8);
            *(uint4*)&ks[r * 264 + col8 * 8] = pk;
        }
        __syncthreads();
        for (int s = 0; s < 8; s++) {
            bf16x8 a = *(const bf16x8*)&qs[(ib * 16 + l15) * 264 + s * 32 + quad * 8];
            bf16x8 bb = *(const bf16x8*)&ks[(jb * 16 + l15) * 264 + s * 32 + quad * 8];
            acc = MFMA(a, bb, acc);  // B loaded A-style == k^T
        }
    }
    float* sp = sims + (size_t)bh * 1024;
    for (int r = 0; r < 4; r++) {
        int row = ib * 16 + quad * 4 + r, col = jb * 16 + l15;
        atomicAdd(sp + row * 32 + col, acc[r]);
    }
}

// K6: scale (temperature * 8 / norms) + softmax over 32 cols -> attn bf16. grid=128, block=64
__global__ __launch_bounds__(64) void k_soft(const float* __restrict__ sims,
                                             const float* __restrict__ normsq,
                                             const float* __restrict__ temp, u16* __restrict__ attn) {
    int bh = blockIdx.x;
    int b = bh >> 3, h = bh & 7;
    __shared__ float scq[32], sck[32];
    int t = threadIdx.x;
    if (t < 32)
        scq[t] = expf(temp[h]) * 8.0f / fmaxf(sqrtf(normsq[b * 512 + h * 32 + t]), 1e-12f);
    else {
        int d = t - 32;
        sck[d] = 1.0f / fmaxf(sqrtf(normsq[b * 512 + 256 + h * 32 + d]), 1e-12f);
    }
    __syncthreads();
    if (t < 32) {
        float row[32];
        float m = -1e30f;
        const float* sp = sims + (size_t)bh * 1024 + t * 32;
        float sq = scq[t];
        for (int j = 0; j < 32; j++) { float v = sp[j] * sq * sck[j]; row[j] = v; m = fmaxf(m, v); }
        float s = 0.f;
        for (int j = 0; j < 32; j++) { float p = expf(row[j] - m); row[j] = p; s += p; }
        float inv = 1.f / s;
        u16* ap = attn + (size_t)bh * 1024 + t * 32;
        for (int j = 0; j < 32; j++) ap[j] = f2bf(row[j] * inv);
    }
}

// K7: out^T = v^T . attn^T  per (b,h), chunk of 256 n per block -> oaT[b][n][hd] bf16
// grid = 16*8*16 = 2048
__global__ __launch_bounds__(256) void k_pv(const u16* __restrict__ qkv, const u16* __restrict__ attn,
                                            u16* __restrict__ oaT) {
    int bid = blockIdx.x;
    int nc = bid & 15, h = (bid >> 4) & 7, b = bid >> 7;
    int nb = nc * 256;
    __shared__ u16 vt[256 * 40];  // v^T [n-local][j], chunk-XOR swizzled on j-chunks
    int t = threadIdx.x, w = t >> 6, lane = t & 63, l15 = lane & 15, quad = lane >> 4;
    const u16* ap = attn + (size_t)(b * 8 + h) * 1024;
    bf16x8 a0 = *(const bf16x8*)(ap + l15 * 32 + quad * 8);         // attn rows 0..15 (B-style => attn^T)
    bf16x8 a1 = *(const bf16x8*)(ap + (16 + l15) * 32 + quad * 8);  // attn rows 16..31
    const u16* vp = qkv + ((size_t)(b * 768) + 512 + h * 32) * 4096 + nb;
    int col8 = t & 31, rb = t >> 5;
    for (int i = 0; i < 4; i++) {
        int j = rb + i * 8;
        uint4 p = *(const uint4*)(vp + (size_t)j * 4096 + col8 * 8);
        const u16* us = (const u16*)&p;
        int ch = j >> 3;
        for (int jj = 0; jj < 8; jj++) {
            int nl = col8 * 8 + jj;
            vt[nl * 40 + ((ch ^ (col8 & 3)) << 3) + (j & 7)] = us[jj];
        }
    }
    __syncthreads();
    f32x4 z = {0.f, 0.f, 0.f, 0.f};
    for (int mm = 0; mm < 4; mm++) {
        int nlb = (w * 4 + mm) * 16;
        int nl = nlb + l15;
        bf16x8 vf = *(const bf16x8*)&vt[nl * 40 + ((quad ^ ((nl >> 3) & 3)) << 3)];
        f32x4 d0 = MFMA(vf, a0, z);  // cols = hd 0..15
        f32x4 d1 = MFMA(vf, a1, z);  // cols = hd 16..31
        for (int r = 0; r < 4; r++) {
            int n = nb + nlb + quad * 4 + r;
            size_t base = ((size_t)(b * 4096) + n) * 256 + h * 32;
            oaT[base + l15] = f2bf(d0[r]);
            oaT[base + 16 + l15] = f2bf(d1[r]);
        }
    }
}

extern "C" void kernel_launch(void* const* d_in, const int* in_sizes, int n_in,
                              void* d_out, int out_size, void* d_ws, size_t ws_size,
                              hipStream_t stream) {
    const float* x     = (const float*)d_in[0];
    const float* gamma = (const float*)d_in[1];
    const float* beta  = (const float*)d_in[2];
    const float* Wqkv  = (const float*)d_in[3];
    const float* temp  = (const float*)d_in[4];
    const float* Wout  = (const float*)d_in[5];
    const float* bout  = (const float*)d_in[6];
    float* out = (float*)d_out;

    char* ws = (char*)d_ws;
    size_t off = 0;
    auto alloc = [&](size_t nbytes) -> void* {
        void* p = ws + off;
        off = (off + nbytes + 255) & ~(size_t)255;
        return p;
    };
    u16* xlnT    = (u16*)alloc((size_t)16 * 4096 * 256 * 2);  // 32 MB  (b,n,c) bf16
    u16* WqkvT   = (u16*)alloc((size_t)768 * 256 * 2);
    u16* WoutT   = (u16*)alloc((size_t)256 * 256 * 2);
    u16* qkv     = (u16*)alloc((size_t)16 * 768 * 4096 * 2);  // 96 MB  (b,o,n) bf16
    float* normsq = (float*)alloc((size_t)16 * 512 * 4);
    float* sims   = (float*)alloc((size_t)128 * 1024 * 4);
    u16* attn    = (u16*)alloc((size_t)128 * 1024 * 2);
    u16* oaT     = (u16*)alloc((size_t)16 * 4096 * 256 * 2);  // 32 MB  (b,n,hd) bf16
    (void)ws_size; (void)in_sizes; (void)n_in; (void)out_size;

    hipLaunchKernelGGL(k_ln, dim3(1024), dim3(256), 0, stream, x, gamma, beta, xlnT);
    hipLaunchKernelGGL(k_prep, dim3(768), dim3(256), 0, stream, Wqkv, Wout, WqkvT, WoutT, sims);
    hipLaunchKernelGGL(k_gemm, dim3(3072), dim3(256), 0, stream, WqkvT, xlnT, 6,
                       qkv, (float*)nullptr, (const float*)nullptr, 0);
    hipLaunchKernelGGL(k_norms, dim3(1024), dim3(256), 0, stream, qkv, normsq);
    hipLaunchKernelGGL(k_sim, dim3(256), dim3(256), 0, stream, qkv, sims);
    hipLaunchKernelGGL(k_soft, dim3(128), dim3(64), 0, stream, sims, normsq, temp, attn);
    hipLaunchKernelGGL(k_pv, dim3(2048), dim3(256), 0, stream, qkv, attn, oaT);
    hipLaunchKernelGGL(k_gemm, dim3(1024), dim3(256), 0, stream, WoutT, oaT, 2,
                       (u16*)nullptr, out, bout, 1);
}